// Round 1
// baseline (1472.502 us; speedup 1.0000x reference)
//
#include <hip/hip_runtime.h>
#include <math.h>

// PCDONN: 144 fields (M=9 modes x B=16 batch) of 512x512 complex64 through
// 4 angular-spectrum propagations (all z=0.05 -> same H; last two fuse to H^2),
// 3 amplitude/phase masks, intensity mean over modes, detector-mask readout.
//
// FFT: per-wave Stockham radix-8 (64 lanes x 8 complex regs, 3 stages),
// XOR-swizzled LDS (sig(j)=j^(j>>3)) -> all exchange patterns bank-conflict-free,
// no barriers (single-wave LDS ops are in-order).

constexpr int HW   = 512 * 512;
constexpr int NF   = 144;  // M*B
constexpr int NB   = 16;
constexpr int NM   = 9;
constexpr int NC   = 10;

__device__ __forceinline__ float2 cmul(float2 a, float2 b) {
    return make_float2(a.x * b.x - a.y * b.y, a.x * b.y + a.y * b.x);
}
__device__ __forceinline__ float2 cadd(float2 a, float2 b) { return make_float2(a.x + b.x, a.y + b.y); }
__device__ __forceinline__ float2 csub(float2 a, float2 b) { return make_float2(a.x - b.x, a.y - b.y); }

// multiply by S*i  (S=-1: -i for forward FFT; S=+1: +i for inverse)
template <int S>
__device__ __forceinline__ float2 mulJ(float2 z) {
    return (S < 0) ? make_float2(z.y, -z.x) : make_float2(-z.y, z.x);
}

// twiddle multiply; stored twiddles are forward (angle<0); inverse uses conjugate
template <int S>
__device__ __forceinline__ float2 twmul(float2 a, float2 t) {
    float ty = (S < 0) ? t.y : -t.y;
    return make_float2(a.x * t.x - a.y * ty, a.x * ty + a.y * t.x);
}

// natural-order 8-point DFT (DIT: two DFT4 + combine)
template <int S>
__device__ __forceinline__ void dft8(const float2 a[8], float2 X[8]) {
    float2 e[4], o[4];
    {
        float2 t0 = cadd(a[0], a[4]), t1 = csub(a[0], a[4]);
        float2 u0 = cadd(a[2], a[6]), u1 = mulJ<S>(csub(a[2], a[6]));
        e[0] = cadd(t0, u0); e[1] = cadd(t1, u1); e[2] = csub(t0, u0); e[3] = csub(t1, u1);
    }
    {
        float2 t0 = cadd(a[1], a[5]), t1 = csub(a[1], a[5]);
        float2 u0 = cadd(a[3], a[7]), u1 = mulJ<S>(csub(a[3], a[7]));
        o[0] = cadd(t0, u0); o[1] = cadd(t1, u1); o[2] = csub(t0, u0); o[3] = csub(t1, u1);
    }
    const float C = 0.70710678118654752f;
    float2 w1 = make_float2(C, (S < 0) ? -C : C);
    float2 w3 = make_float2(-C, (S < 0) ? -C : C);
    o[1] = cmul(o[1], w1);
    o[2] = mulJ<S>(o[2]);
    o[3] = cmul(o[3], w3);
    X[0] = cadd(e[0], o[0]); X[4] = csub(e[0], o[0]);
    X[1] = cadd(e[1], o[1]); X[5] = csub(e[1], o[1]);
    X[2] = cadd(e[2], o[2]); X[6] = csub(e[2], o[2]);
    X[3] = cadd(e[3], o[3]); X[7] = csub(e[3], o[3]);
}

__device__ __forceinline__ int sig(int j) { return (j ^ (j >> 3)) & 511; }

__device__ __forceinline__ void init_tw(int t, float2* tw0, float2* tw1) {
    const float TWO_PI = 6.28318530717958647693f;
    tw0[0] = make_float2(1.f, 0.f);
    tw1[0] = make_float2(1.f, 0.f);
    float a0 = -TWO_PI * (float)t / 512.0f;
    float a1 = -TWO_PI * (float)(t >> 3) / 64.0f;
#pragma unroll
    for (int r = 1; r < 8; ++r) {
        float s, c;
        sincosf(a0 * (float)r, &s, &c); tw0[r] = make_float2(c, s);
        sincosf(a1 * (float)r, &s, &c); tw1[r] = make_float2(c, s);
    }
}

// 512-point FFT, one wave. On entry v[r] = x[t+64r] (natural); on exit v[r] = X[t+64r].
// lds: 512-float2 scratch for this wave; slot(j) = (sig(j)+rot)&511.
template <int S>
__device__ __forceinline__ void fft512(float2 v[8], float2* lds, int t,
                                       const float2* tw0, const float2* tw1, int rot) {
    float2 b[8];
    // stage 0: n=512, s=1, p=t
    dft8<S>(v, b);
#pragma unroll
    for (int r = 1; r < 8; ++r) b[r] = twmul<S>(b[r], tw0[r]);
#pragma unroll
    for (int r = 0; r < 8; ++r) lds[(sig(8 * t + r) + rot) & 511] = b[r];
    // stage 1: n=64, s=8, q=t&7, p=t>>3
#pragma unroll
    for (int r = 0; r < 8; ++r) v[r] = lds[(sig(t + 64 * r) + rot) & 511];
    dft8<S>(v, b);
#pragma unroll
    for (int r = 1; r < 8; ++r) b[r] = twmul<S>(b[r], tw1[r]);
    {
        int q = t & 7, p = t >> 3;
#pragma unroll
        for (int r = 0; r < 8; ++r) lds[(sig(q + 64 * p + 8 * r) + rot) & 511] = b[r];
    }
    // stage 2: n=8, s=64, p=0 (no twiddle), natural-order output
#pragma unroll
    for (int r = 0; r < 8; ++r) v[r] = lds[(sig(t + 64 * r) + rot) & 511];
    dft8<S>(v, b);
#pragma unroll
    for (int r = 0; r < 8; ++r) v[r] = b[r];
}

// ---- init: T tables (3 layers) + H + H^2 -------------------------------------
__global__ __launch_bounds__(256) void k_init(const float* __restrict__ amp,
                                              const float* __restrict__ ph,
                                              float2* __restrict__ Ttab,
                                              float2* __restrict__ Htab,
                                              float2* __restrict__ Htab2) {
    int idx = blockIdx.x * 256 + threadIdx.x;
#pragma unroll
    for (int l = 0; l < 3; ++l) {
        float a = amp[l * HW + idx], p = ph[l * HW + idx];
        float s, c; sincosf(p, &s, &c);
        Ttab[l * HW + idx] = make_float2(a * c, a * s);
    }
    int i = idx >> 9, j = idx & 511;
    const float fscale = 244.140625f;  // 1/(512*8e-6), exact
    float fi = (float)(i < 256 ? i : i - 512) * fscale;
    float fj = (float)(j < 256 ? j : j - 512) * fscale;
    const float lam = 5.32e-07f;
    float ax = lam * fi, ay = lam * fj;
    float arg = 1.0f - ax * ax;
    arg = arg - ay * ay;
    float sq = sqrtf(fmaxf(arg, 0.0f));
    const float kz = (float)(2.0 * 3.14159265358979323846 / 5.32e-07 * 0.05);
    float th = kz * sq;
    float s, c; sincosf(th, &s, &c);
    Htab[idx]  = make_float2(c, s);
    Htab2[idx] = make_float2(c * c - s * s, 2.f * c * s);  // H^2 (fused props 3+4)
}

// ---- K0: E_in * T0, forward row FFT ------------------------------------------
__global__ __launch_bounds__(256) void k_first(const float* __restrict__ xamp,
                                               const float* __restrict__ noise,
                                               const float2* __restrict__ T0,
                                               float2* __restrict__ field) {
    __shared__ float2 scr[4][512];
    int t = threadIdx.x & 63, wv = threadIdx.x >> 6;
    int wid = blockIdx.x * 4 + wv;       // [0, 144*512)
    int row = wid & 511, f = wid >> 9;   // f = m*16+b
    int b = f & 15, m = f >> 4;
    float fac = 0.5f * (float)(m + 1);
    float2 tw0[8], tw1[8];
    init_tw(t, tw0, tw1);
    const float*  xr = xamp + (size_t)b * HW + row * 512;
    const float*  nr = noise + (size_t)f * HW + row * 512;
    const float2* Tr = T0 + row * 512;
    float2 v[8];
#pragma unroll
    for (int r = 0; r < 8; ++r) {
        int w = t + 64 * r;
        float pn = nr[w] * fac;
        float s, c; sincosf(pn, &s, &c);
        float xa = xr[w];
        v[r] = cmul(make_float2(xa * c, xa * s), Tr[w]);
    }
    fft512<-1>(v, scr[wv], t, tw0, tw1, 0);
    float2* out = field + (size_t)f * HW + row * 512;
#pragma unroll
    for (int r = 0; r < 8; ++r) out[t + 64 * r] = v[r];
}

// ---- K_col: column FFT -> xH -> inverse column FFT (in place) ----------------
__global__ __launch_bounds__(256) void k_col(float2* __restrict__ field,
                                             const float2* __restrict__ Htab) {
    __shared__ float2 tile[16 * 512];  // 64 KB, swizzled columns
    int tid = threadIdx.x, t = tid & 63, wv = tid >> 6;
    int fidx = blockIdx.x >> 5;
    int c0   = (blockIdx.x & 31) << 4;
    float2* fb = field + (size_t)fidx * HW;
    int lcL = tid & 15, hsub = tid >> 4;
    for (int it = 0; it < 32; ++it) {
        int h = it * 16 + hsub;
        tile[lcL * 512 + ((sig(h) + 2 * lcL) & 511)] = fb[(size_t)h * 512 + c0 + lcL];
    }
    __syncthreads();
    float2 tw0[8], tw1[8];
    init_tw(t, tw0, tw1);
    for (int cc = 0; cc < 4; ++cc) {
        int lc = wv * 4 + cc, col = c0 + lc, rot = 2 * lc;
        float2* lds = tile + lc * 512;
        float2 v[8];
#pragma unroll
        for (int r = 0; r < 8; ++r) v[r] = lds[(sig(t + 64 * r) + rot) & 511];
        fft512<-1>(v, lds, t, tw0, tw1, rot);
        const float2* Hr = Htab + (size_t)col * 512;  // H symmetric -> coalesced
#pragma unroll
        for (int r = 0; r < 8; ++r) v[r] = cmul(v[r], Hr[t + 64 * r]);
        fft512<1>(v, lds, t, tw0, tw1, rot);
        const float inv = 1.0f / 512.0f;
#pragma unroll
        for (int r = 0; r < 8; ++r) {
            v[r].x *= inv; v[r].y *= inv;
            lds[(sig(t + 64 * r) + rot) & 511] = v[r];
        }
    }
    __syncthreads();
    for (int it = 0; it < 32; ++it) {
        int h = it * 16 + hsub;
        fb[(size_t)h * 512 + c0 + lcL] = tile[lcL * 512 + ((sig(h) + 2 * lcL) & 511)];
    }
}

// ---- K_row: inverse row FFT -> xT -> forward row FFT (in place) --------------
__global__ __launch_bounds__(256) void k_row(float2* __restrict__ field,
                                             const float2* __restrict__ Tl) {
    __shared__ float2 scr[4][512];
    int t = threadIdx.x & 63, wv = threadIdx.x >> 6;
    int wid = blockIdx.x * 4 + wv;
    int row = wid & 511, f = wid >> 9;
    float2 tw0[8], tw1[8];
    init_tw(t, tw0, tw1);
    float2* g = field + (size_t)f * HW + row * 512;
    const float2* Tr = Tl + row * 512;
    float2 v[8];
#pragma unroll
    for (int r = 0; r < 8; ++r) v[r] = g[t + 64 * r];
    fft512<1>(v, scr[wv], t, tw0, tw1, 0);
    const float inv = 1.0f / 512.0f;
#pragma unroll
    for (int r = 0; r < 8; ++r) {
        float2 z = make_float2(v[r].x * inv, v[r].y * inv);
        v[r] = cmul(z, Tr[t + 64 * r]);
    }
    fft512<-1>(v, scr[wv], t, tw0, tw1, 0);
#pragma unroll
    for (int r = 0; r < 8; ++r) g[t + 64 * r] = v[r];
}

// ---- K_final: inverse row FFT, |.|^2 mean over modes, detector dot -----------
__global__ __launch_bounds__(256) void k_final(const float2* __restrict__ field,
                                               const float* __restrict__ mask,
                                               float* __restrict__ out) {
    __shared__ float2 scr[4][512];
    int t = threadIdx.x & 63, wv = threadIdx.x >> 6;
    int wid = blockIdx.x * 4 + wv;  // [0, 16*512)
    int row = wid & 511, b = wid >> 9;
    float2 tw0[8], tw1[8];
    init_tw(t, tw0, tw1);
    float inten[8];
#pragma unroll
    for (int r = 0; r < 8; ++r) inten[r] = 0.f;
    for (int m = 0; m < NM; ++m) {
        const float2* g = field + (size_t)(m * NB + b) * HW + row * 512;
        float2 v[8];
#pragma unroll
        for (int r = 0; r < 8; ++r) v[r] = g[t + 64 * r];
        fft512<1>(v, scr[wv], t, tw0, tw1, 0);
#pragma unroll
        for (int r = 0; r < 8; ++r) inten[r] += v[r].x * v[r].x + v[r].y * v[r].y;
    }
    const float sc = 1.0f / (512.0f * 512.0f * 9.0f);  // ifft scale^2 * mean
    const float* mrow = mask + row * 512;
#pragma unroll
    for (int c = 0; c < NC; ++c) {
        float s = 0.f;
#pragma unroll
        for (int r = 0; r < 8; ++r) s += inten[r] * mrow[(size_t)c * HW + t + 64 * r];
        s *= sc;
#pragma unroll
        for (int off = 32; off; off >>= 1) s += __shfl_xor(s, off, 64);
        if (t == 0) atomicAdd(&out[b * NC + c], s);
    }
}

extern "C" void kernel_launch(void* const* d_in, const int* in_sizes, int n_in,
                              void* d_out, int out_size, void* d_ws, size_t ws_size,
                              hipStream_t stream) {
    const float* xamp  = (const float*)d_in[0];
    const float* noise = (const float*)d_in[1];
    const float* amp   = (const float*)d_in[2];
    const float* ph    = (const float*)d_in[3];
    const float* mask  = (const float*)d_in[4];

    char* ws = (char*)d_ws;
    float2* field = (float2*)ws;
    size_t off = (size_t)NF * HW * sizeof(float2);      // 302 MB
    float2* Ttab = (float2*)(ws + off); off += 3ull * HW * sizeof(float2);
    float2* Htab = (float2*)(ws + off); off += (size_t)HW * sizeof(float2);
    float2* Htab2 = (float2*)(ws + off);

    float* out = (float*)d_out;
    hipMemsetAsync(d_out, 0, (size_t)out_size * sizeof(float), stream);

    k_init<<<HW / 256, 256, 0, stream>>>(amp, ph, Ttab, Htab, Htab2);
    k_first<<<NF * 512 / 4, 256, 0, stream>>>(xamp, noise, Ttab, field);
    k_col<<<NF * 32, 256, 0, stream>>>(field, Htab);            // prop 1 (h-dim)
    k_row<<<NF * 512 / 4, 256, 0, stream>>>(field, Ttab + HW);  // ifft_w, xT1, fft_w
    k_col<<<NF * 32, 256, 0, stream>>>(field, Htab);            // prop 2
    k_row<<<NF * 512 / 4, 256, 0, stream>>>(field, Ttab + 2 * HW);
    k_col<<<NF * 32, 256, 0, stream>>>(field, Htab2);           // props 3+4 fused (H^2)
    k_final<<<NB * 512 / 4, 256, 0, stream>>>(field, mask, out);
}